// Round 1
// baseline (220.417 us; speedup 1.0000x reference)
//
#include <hip/hip_runtime.h>

// RNN car-following: NVEH=16384, NT=256, H=20.
// R10: VALU-issue diet on R9's register-resident recurrence. Structure
// unchanged (lane (q,c) owns items 5q..5q+4 of vehicle c; B-frag lane-local;
// no LDS/shuffles/barriers in loop). Changes vs R9:
//  - rcp fusion: s(i)*tanh(g) = (1-eg)/[(1+ei)(1+eg)], s(o)*tanh(c) =
//    (1-ec)/[(1+eo)(1+ec)]  -> 3 rcp + 5 exp per item (was 5+5).
//  - scaled-c domain: cst2 = N2L*c, so ec = EXP2(c2) directly (drops the
//    N2L*cc mul). fminf(c2,80) clamp guards the fused denominator.
//  - packed fp32 gate args: (z0,z1)/(z2,z3) are adjacent VGPRs from MFMA
//    -> v_pk_fma_f32 via f32x2.
//  - B-frag as u32x4 dwords built with v_cvt_pk_bf16_f32 (HW RNE ==
//    manual RNE): 4 cvt_pk replace ~25 round/pack ops; hi via shl/and.
//  - z[5] (acc tile) MFMA issued first; rq residual tree-reduced.
// Numerics: bf16 rounding points bit-identical to R9; gate algebra is
// ulp-equivalent; all fp32 residual corrections retained.

#define NVEH 16384
#define NT   256
#define H    20

typedef float f32x4  __attribute__((ext_vector_type(4)));
typedef float f32x2  __attribute__((ext_vector_type(2)));
typedef short bf16x8 __attribute__((ext_vector_type(8)));
typedef unsigned u32x4 __attribute__((ext_vector_type(4)));

#if __has_builtin(__builtin_amdgcn_exp2f)
#define EXP2(x) __builtin_amdgcn_exp2f(x)
#else
#define EXP2(x) __expf((x) * 0.69314718056f)
#endif
#define RCP(x) __builtin_amdgcn_rcpf(x)

__device__ __forceinline__ short f2bf(float f) {     // RNE float->bf16
    unsigned u = __builtin_bit_cast(unsigned, f);
    u += 0x7fffu + ((u >> 16) & 1u);
    return (short)(u >> 16);
}
__device__ __forceinline__ float bf2f(short s) {
    return __builtin_bit_cast(float, ((unsigned)(unsigned short)s) << 16);
}
__device__ __forceinline__ unsigned cvtpk(float lo, float hi) {  // [bf(lo)|bf(hi)<<16], RNE
    unsigned r;
    asm("v_cvt_pk_bf16_f32 %0, %1, %2" : "=v"(r) : "v"(lo), "v"(hi));
    return r;
}

__global__ __launch_bounds__(256, 1) void rnncf_kernel(
    const float* __restrict__ lead,   // (NVEH, NT, 2)
    const float* __restrict__ inits,  // (NVEH, 2)
    const float* __restrict__ h0,     // (NVEH, H)
    const float* __restrict__ c0,     // (NVEH, H)
    const float* __restrict__ W,      // (3, 80)
    const float* __restrict__ U,      // (20, 80)
    const float* __restrict__ b,      // (80,)
    const float* __restrict__ Wd,     // (20,)
    const float* __restrict__ bd,     // (1,)
    float* __restrict__ out)
{
    // UT: 6 tiles x 16 rows x 32 k (bf16). Gate tiles T=0..4: row m =
    // gate(m&3) of item j=5*(m>>2)+T, scaled log2e (2log2e for g).
    // k-content (kq=k>>3, ko=k&7): ko<5 -> U[5kq+ko][col]; ko==5 -> 0 (res);
    // ko==6 -> kq<3 ? W[kq][col] : b[col]; ko==7 -> 0.
    // Tile 5: rows with (m&3)==0: acc row: ko<5 -> 7*Wd[5kq+ko], ko==5 -> 1.0,
    // else 0 (bias added in fp32). Other rows 0.
    __shared__ __attribute__((aligned(16))) short UT[96 * 32];

    const int tid  = threadIdx.x;
    const int lane = tid & 63;
    const int q    = lane >> 4;       // k-window / item-group
    const int c    = lane & 15;       // vehicle column
    const float L2E = 1.44269504f;
    const float N2L = -2.f * L2E;     // -2*log2(e)
    const float P2L =  2.f * L2E;
    const float IN2L = -0.34657359028f;   // 1/N2L
    const float bdv = bd[0];
    const float biasK = 7.f * bdv - 4.f;

    // ---- build UT ----
    for (int idx = tid; idx < 96 * 32; idx += 256) {
        int row = idx >> 5, k = idx & 31;
        int T = row >> 4, m = row & 15;
        int kq = k >> 3, ko = k & 7;
        float v = 0.f;
        if (T < 5) {
            int g = m & 3, j = 5 * (m >> 2) + T;
            int col = g * 20 + j;
            if      (ko < 5)             v = U[(5 * kq + ko) * 80 + col];
            else if (ko == 6 && kq < 3)  v = W[kq * 80 + col];
            else if (ko == 6)            v = b[col];
            v *= (g == 2) ? (2.f * L2E) : L2E;
        } else if ((m & 3) == 0) {
            if      (ko < 5)  v = 7.f * Wd[5 * kq + ko];
            else if (ko == 5) v = 1.f;
        }
        UT[idx] = f2bf(v);
    }

    const int veh = blockIdx.x * 64 + (tid >> 6) * 16 + c;

    // ---- per-item constants: items j = 5q+T, T=0..4 ----
    f32x2 wif[5], wgo[5];
    float wd7[5], w7b[5];
#pragma unroll
    for (int T = 0; T < 5; ++T) {
        int j = 5 * q + T;
        float wc[4];
#pragma unroll
        for (int g = 0; g < 4; ++g) {
            int col = g * 20 + j;
            wc[g] = -(-0.001f * W[col] + 0.0025f * W[80 + col])
                  * ((g == 2) ? (2.f * L2E) : L2E);   // negated coeff
        }
        f32x2 a = {wc[0], wc[1]}; wif[T] = a;
        f32x2 d = {wc[2], wc[3]}; wgo[T] = d;
        float w7 = 7.f * Wd[j];
        wd7[T] = w7;
        w7b[T] = bf2f(f2bf(w7));
    }

    // ---- init: h0 -> B dwords (registers), res partial, acc_{-1} ----
    u32x4 B;
    float cst2[5], hl[5];
    float rpart = 0.f, apart = 0.f;
    {
        unsigned w0 = 0, w1 = 0, w2 = 0;
#pragma unroll
        for (int T = 0; T < 5; ++T) {
            int j = 5 * q + T;
            float hv = h0[veh * H + j];
            cst2[T] = N2L * c0[veh * H + j];
            hl[T] = hv;
            short hb = f2bf(hv);
            float hi = bf2f(hb);
            unsigned hs = (unsigned)(unsigned short)hb;
            if      (T == 0) w0  = hs;
            else if (T == 1) w0 |= hs << 16;
            else if (T == 2) w1  = hs;
            else if (T == 3) w1 |= hs << 16;
            else             w2  = hs;
            rpart = __builtin_fmaf(hv, wd7[T], rpart);
            rpart = __builtin_fmaf(-hi, w7b[T], rpart);
            apart = __builtin_fmaf(hv, wd7[T], apart);
        }
        w2 |= (unsigned)(unsigned short)f2bf(rpart) << 16;
        B[0] = w0; B[1] = w1; B[2] = w2;
    }
    apart += __shfl_xor(apart, 16);
    apart += __shfl_xor(apart, 32);

    float pos = inits[veh * 2 + 0];
    float spd = inits[veh * 2 + 1];
    {
        float a = apart + biasK;          // acc_{-1}, exact fp32
        pos -= 0.1f * a;                  // virtual lagged state
        spd -= 0.1f * a;
    }

    // ---- x~_0 and lead pipeline (depth 2) ----
    const float2* lp0 = (const float2*)lead + (long)veh * NT;
    {
        float2 lu = lp0[0];
        float xv = (q == 0) ? (lu.x - pos) * 0.01f
                 : (q == 1) ? spd * 0.025f
                 : (q == 2) ? lu.y * 0.025f
                            : 1.0f;       // one-slot
        B[3] = (unsigned)(unsigned short)f2bf(xv);
    }
    float2 lA = lp0[1];
    float2 lB = lp0[2];

    __syncthreads();   // UT visibility; only barrier in the kernel

    // ---- loop-invariant A fragments (row c, k-slice q) ----
    bf16x8 A[6];
#pragma unroll
    for (int T = 0; T < 6; ++T)
        A[T] = *(const bf16x8*)&UT[(T * 16 + c) * 32 + q * 8];

    for (int t = 0; t < NT; ++t) {
        float2 lu = lA;                   // lead[t+1], loaded 2 iters ago
        lA = lB;
        int tn = t + 3; tn = (tn < NT) ? tn : NT - 1;
        lB = lp0[tn];                     // consumed 2 iters from now

        f32x4 zero = {0.f, 0.f, 0.f, 0.f};
        bf16x8 Bf = __builtin_bit_cast(bf16x8, B);
        // acc tile FIRST: everything downstream gates on z5[0]
        f32x4 z5 = __builtin_amdgcn_mfma_f32_16x16x32_bf16(A[5], Bf, zero, 0, 0, 0);
        f32x4 z[5];
#pragma unroll
        for (int T = 0; T < 5; ++T)
            z[T] = __builtin_amdgcn_mfma_f32_16x16x32_bf16(A[T], Bf, zero, 0, 0, 0);

        // ---- acc_{t-1}: every lane, fp32-accurate ----
        float acc = z5[0] + biasK;
        pos = __builtin_fmaf(0.1f, acc, pos);
        spd = __builtin_fmaf(0.1f, acc, spd);
        if (q == 1 && t > 0)
            out[(size_t)(t - 1) * NVEH + veh] = pos;   // coalesced

        // ---- x~_{t+1}: dword 3 of next B-frag ----
        float xv = (q == 0) ? (lu.x - pos) * 0.01f
                 : (q == 1) ? spd * 0.025f
                 : (q == 2) ? lu.y * 0.025f
                            : 1.0f;
        unsigned d3 = cvtpk(xv, 0.f);

        // ---- 5 items (j=5q+T): gates lane-local in z[T][0..3] ----
        f32x2 acc2 = {acc, acc};
#pragma unroll
        for (int T = 0; T < 5; ++T) {
            f32x2 zif = __builtin_shufflevector(z[T], z[T], 0, 1);  // adjacent regs
            f32x2 zgo = __builtin_shufflevector(z[T], z[T], 2, 3);
            f32x2 aif = __builtin_elementwise_fma(acc2, wif[T], -zif);  // v_pk_fma_f32
            f32x2 ago = __builtin_elementwise_fma(acc2, wgo[T], -zgo);
            float ei = EXP2(aif[0]);      // e^{-i}
            float ef = EXP2(aif[1]);      // e^{-f}
            float eg = EXP2(ago[0]);      // e^{-2g}
            float eo = EXP2(ago[1]);      // e^{-o}
            float pi = 1.f + ei, pf = 1.f + ef, pg = 1.f + eg, po = 1.f + eo;
            float Rig = RCP(pi * pg);     // fused: s(i)*tanh(g) denom
            float ffv = RCP(pf);          // s(f)
            float uu  = __builtin_fmaf(P2L, eg, N2L);   // N2L*(1-eg)
            float t2  = uu * Rig;                        // N2L * s(i)*tanh(g)
            float c2  = __builtin_fmaf(ffv, cst2[T], t2);  // scaled c
            cst2[T] = c2;
            float ec = EXP2(__builtin_fminf(c2, 80.f)); // e^{-2c}, clamped
            float pc = 1.f + ec;
            float Roc = RCP(po * pc);     // fused: s(o)*tanh(c) denom
            hl[T] = (1.f - ec) * Roc;     // h = s(o)*tanh(c)
        }

        // ---- pack h -> bf16 dwords (HW RNE) + fp32 residual (tree) ----
        unsigned d0 = cvtpk(hl[0], hl[1]);
        unsigned d1 = cvtpk(hl[2], hl[3]);
        float hi0 = __builtin_bit_cast(float, d0 << 16);
        float hi1 = __builtin_bit_cast(float, d0 & 0xffff0000u);
        float hi2 = __builtin_bit_cast(float, d1 << 16);
        float hi3 = __builtin_bit_cast(float, d1 & 0xffff0000u);
        unsigned u4 = __builtin_bit_cast(unsigned, hl[4]);
        float hi4 = __builtin_bit_cast(float, (u4 + 0x7fffu + ((u4 >> 16) & 1u)) & 0xffff0000u);
        float r0 = __builtin_fmaf(hl[0], wd7[0], -(hi0 * w7b[0]));
        float r1 = __builtin_fmaf(hl[1], wd7[1], -(hi1 * w7b[1]));
        float r2 = __builtin_fmaf(hl[2], wd7[2], -(hi2 * w7b[2]));
        float r3 = __builtin_fmaf(hl[3], wd7[3], -(hi3 * w7b[3]));
        float r4 = __builtin_fmaf(hl[4], wd7[4], -(hi4 * w7b[4]));
        float rq = ((r0 + r1) + (r2 + r3)) + r4;
        unsigned d2 = cvtpk(hl[4], rq);
        B[0] = d0; B[1] = d1; B[2] = d2; B[3] = d3;
    }

    // ---- tail: acc_255 exact from fp32 hl ----
    float ap = 0.f;
#pragma unroll
    for (int T = 0; T < 5; ++T) ap = __builtin_fmaf(hl[T], wd7[T], ap);
    ap += __shfl_xor(ap, 16);
    ap += __shfl_xor(ap, 32);
    float accF = ap + biasK;
    if (q == 1) out[(size_t)(NT - 1) * NVEH + veh] = pos + 0.1f * accF;
    if (q == 2) out[(size_t)NT * NVEH + veh]       = spd + 0.1f * accF;

    // ---- final h, c (c unscaled from cst2) ----
    const int oH = NT * NVEH + NVEH;
    const int oC = oH + NVEH * H;
#pragma unroll
    for (int T = 0; T < 5; ++T) {
        int j = 5 * q + T;
        out[oH + veh * H + j] = hl[T];
        out[oC + veh * H + j] = cst2[T] * IN2L;
    }
}

extern "C" void kernel_launch(void* const* d_in, const int* in_sizes, int n_in,
                              void* d_out, int out_size, void* d_ws, size_t ws_size,
                              hipStream_t stream) {
    const float* lead  = (const float*)d_in[0];
    const float* inits = (const float*)d_in[1];
    const float* h0    = (const float*)d_in[2];
    const float* c0    = (const float*)d_in[3];
    const float* W     = (const float*)d_in[4];
    const float* U     = (const float*)d_in[5];
    const float* b     = (const float*)d_in[6];
    const float* Wd    = (const float*)d_in[7];
    const float* bd    = (const float*)d_in[8];
    float* out = (float*)d_out;

    rnncf_kernel<<<NVEH / 64, 256, 0, stream>>>(lead, inits, h0, c0, W, U, b, Wd, bd, out);
}

// Round 2
// 210.013 us; speedup vs baseline: 1.0495x; 1.0495x over previous
//
#include <hip/hip_runtime.h>

// RNN car-following: NVEH=16384, NT=256, H=20.
// R11: R9 structure EXACTLY (per-item Bf insert, manual RNE, scalar fmas,
// serial rq — the known-good 148us schedule), plus only the two pure
// op-removals from R10 (which regressed when bundled with inline-asm
// cvt_pk and f32x2 restructuring — see m240: asm cvt_pk is -37%):
//  - rcp fusion: s(i)*tanh(g) = (1-eg)/[(1+ei)(1+eg)], s(o)*tanh(c) =
//    (1-ec)/[(1+eo)(1+ec)]  -> 3 rcp + 5 exp per item (was 5+5).
//  - scaled-c domain: cst2 = -2*log2e*c, so ec = EXP2(c2) directly;
//    uu = fma(P2L, eg, N2L) folds the N2L mul. fminf(c2,80) clamp keeps
//    the fused o-denominator NaN-free (h -> -sigma(o) saturation limit).
// Numerics: bf16 rounding points bit-identical to R9; gate algebra is
// ulp-equivalent; all fp32 residual corrections retained.

#define NVEH 16384
#define NT   256
#define H    20

typedef float f32x4  __attribute__((ext_vector_type(4)));
typedef short bf16x8 __attribute__((ext_vector_type(8)));

#if __has_builtin(__builtin_amdgcn_exp2f)
#define EXP2(x) __builtin_amdgcn_exp2f(x)
#else
#define EXP2(x) __expf((x) * 0.69314718056f)
#endif
#define RCP(x) __builtin_amdgcn_rcpf(x)

__device__ __forceinline__ short f2bf(float f) {     // RNE float->bf16
    unsigned u = __builtin_bit_cast(unsigned, f);
    u += 0x7fffu + ((u >> 16) & 1u);
    return (short)(u >> 16);
}
__device__ __forceinline__ float bf2f(short s) {
    return __builtin_bit_cast(float, ((unsigned)(unsigned short)s) << 16);
}

__global__ __launch_bounds__(256, 1) void rnncf_kernel(
    const float* __restrict__ lead,   // (NVEH, NT, 2)
    const float* __restrict__ inits,  // (NVEH, 2)
    const float* __restrict__ h0,     // (NVEH, H)
    const float* __restrict__ c0,     // (NVEH, H)
    const float* __restrict__ W,      // (3, 80)
    const float* __restrict__ U,      // (20, 80)
    const float* __restrict__ b,      // (80,)
    const float* __restrict__ Wd,     // (20,)
    const float* __restrict__ bd,     // (1,)
    float* __restrict__ out)
{
    // UT: 6 tiles x 16 rows x 32 k (bf16). Gate tiles T=0..4: row m =
    // gate(m&3) of item j=5*(m>>2)+T, scaled log2e (2log2e for g).
    // k-content (kq=k>>3, ko=k&7): ko<5 -> U[5kq+ko][col]; ko==5 -> 0 (res);
    // ko==6 -> kq<3 ? W[kq][col] : b[col]; ko==7 -> 0.
    // Tile 5: rows with (m&3)==0: acc row: ko<5 -> 7*Wd[5kq+ko], ko==5 -> 1.0,
    // else 0 (bias added in fp32). Other rows 0.
    __shared__ __attribute__((aligned(16))) short UT[96 * 32];

    const int tid  = threadIdx.x;
    const int lane = tid & 63;
    const int q    = lane >> 4;       // k-window / item-group
    const int c    = lane & 15;       // vehicle column
    const float L2E = 1.44269504f;
    const float N2L = -2.f * L2E;     // -2*log2(e)
    const float P2L =  2.f * L2E;
    const float IN2L = -0.34657359028f;   // 1/N2L
    const float bdv = bd[0];
    const float biasK = 7.f * bdv - 4.f;

    // ---- build UT ----
    for (int idx = tid; idx < 96 * 32; idx += 256) {
        int row = idx >> 5, k = idx & 31;
        int T = row >> 4, m = row & 15;
        int kq = k >> 3, ko = k & 7;
        float v = 0.f;
        if (T < 5) {
            int g = m & 3, j = 5 * (m >> 2) + T;
            int col = g * 20 + j;
            if      (ko < 5)             v = U[(5 * kq + ko) * 80 + col];
            else if (ko == 6 && kq < 3)  v = W[kq * 80 + col];
            else if (ko == 6)            v = b[col];
            v *= (g == 2) ? (2.f * L2E) : L2E;
        } else if ((m & 3) == 0) {
            if      (ko < 5)  v = 7.f * Wd[5 * kq + ko];
            else if (ko == 5) v = 1.f;
        }
        UT[idx] = f2bf(v);
    }

    const int veh = blockIdx.x * 64 + (tid >> 6) * 16 + c;

    // ---- per-item constants: items j = 5q+T, T=0..4 ----
    float wcn[5][4], wd7[5], w7b[5];
#pragma unroll
    for (int T = 0; T < 5; ++T) {
        int j = 5 * q + T;
#pragma unroll
        for (int g = 0; g < 4; ++g) {
            int col = g * 20 + j;
            wcn[T][g] = -(-0.001f * W[col] + 0.0025f * W[80 + col])
                      * ((g == 2) ? (2.f * L2E) : L2E);   // negated coeff
        }
        float w7 = 7.f * Wd[j];
        wd7[T] = w7;
        w7b[T] = bf2f(f2bf(w7));
    }

    // ---- init: h0 -> B-frag (registers), res partial, acc_{-1} ----
    bf16x8 Bf = {0, 0, 0, 0, 0, 0, 0, 0};
    float cst2[5], hl[5];
    float rpart = 0.f, apart = 0.f;
#pragma unroll
    for (int T = 0; T < 5; ++T) {
        int j = 5 * q + T;
        float hv = h0[veh * H + j];
        cst2[T] = N2L * c0[veh * H + j];
        hl[T] = hv;
        short hb = f2bf(hv);
        float hi = bf2f(hb);
        Bf[T] = hb;
        rpart = __builtin_fmaf(hv, wd7[T], rpart);
        rpart = __builtin_fmaf(-hi, w7b[T], rpart);
        apart = __builtin_fmaf(hv, wd7[T], apart);
    }
    Bf[5] = f2bf(rpart);
    apart += __shfl_xor(apart, 16);
    apart += __shfl_xor(apart, 32);

    float pos = inits[veh * 2 + 0];
    float spd = inits[veh * 2 + 1];
    {
        float a = apart + biasK;          // acc_{-1}, exact fp32
        pos -= 0.1f * a;                  // virtual lagged state
        spd -= 0.1f * a;
    }

    // ---- x~_0 and lead pipeline (depth 2) ----
    const float2* lp0 = (const float2*)lead + (long)veh * NT;
    {
        float2 lu = lp0[0];
        float xv = (q == 0) ? (lu.x - pos) * 0.01f
                 : (q == 1) ? spd * 0.025f
                            : lu.y * 0.025f;
        if (q < 3) Bf[6] = f2bf(xv);
        else       Bf[6] = (short)0x3F80;   // one-slot (1.0 bf16)
    }
    float2 lA = lp0[1];
    float2 lB = lp0[2];

    __syncthreads();   // UT visibility; only barrier in the kernel

    // ---- loop-invariant A fragments (row c, k-slice q) ----
    bf16x8 A[6];
#pragma unroll
    for (int T = 0; T < 6; ++T)
        A[T] = *(const bf16x8*)&UT[(T * 16 + c) * 32 + q * 8];

    for (int t = 0; t < NT; ++t) {
        float2 lu = lA;                   // lead[t+1], loaded 2 iters ago
        lA = lB;
        int tn = t + 3; tn = (tn < NT) ? tn : NT - 1;
        lB = lp0[tn];                     // consumed 2 iters from now

        f32x4 zero = {0.f, 0.f, 0.f, 0.f};
        // acc tile FIRST: everything downstream gates on z5[0]
        f32x4 z5 = __builtin_amdgcn_mfma_f32_16x16x32_bf16(A[5], Bf, zero, 0, 0, 0);
        f32x4 z[5];
#pragma unroll
        for (int T = 0; T < 5; ++T)
            z[T] = __builtin_amdgcn_mfma_f32_16x16x32_bf16(A[T], Bf, zero, 0, 0, 0);

        // ---- acc_{t-1}: every lane, fp32-accurate ----
        float acc = z5[0] + biasK;
        pos = __builtin_fmaf(0.1f, acc, pos);
        spd = __builtin_fmaf(0.1f, acc, spd);
        if (q == 1 && t > 0)
            out[(size_t)(t - 1) * NVEH + veh] = pos;   // coalesced

        // ---- x~_{t+1} into own B-frag slot ----
        {
            float xv = (q == 0) ? (lu.x - pos) * 0.01f
                     : (q == 1) ? spd * 0.025f
                                : lu.y * 0.025f;
            if (q < 3) Bf[6] = f2bf(xv);
        }

        // ---- 5 items (j=5q+T): gates lane-local in z[T][0..3] ----
        float rq = 0.f;
#pragma unroll
        for (int T = 0; T < 5; ++T) {
            float ei = EXP2(__builtin_fmaf(acc, wcn[T][0], -z[T][0]));  // e^{-i}
            float ef = EXP2(__builtin_fmaf(acc, wcn[T][1], -z[T][1]));  // e^{-f}
            float eg = EXP2(__builtin_fmaf(acc, wcn[T][2], -z[T][2]));  // e^{-2g}
            float eo = EXP2(__builtin_fmaf(acc, wcn[T][3], -z[T][3]));  // e^{-o}
            float ff  = RCP(1.f + ef);                   // s(f)
            float Rig = RCP((1.f + ei) * (1.f + eg));    // fused i/g denom
            float uu  = __builtin_fmaf(P2L, eg, N2L);    // N2L*(1-eg)
            float c2  = __builtin_fmaf(ff, cst2[T], uu * Rig);  // scaled c
            cst2[T] = c2;
            float ec = EXP2(__builtin_fminf(c2, 80.f));  // e^{-2c}, clamped
            float Roc = RCP((1.f + eo) * (1.f + ec));    // fused o/c denom
            float hh = (1.f - ec) * Roc;                 // s(o)*tanh(c)
            hl[T] = hh;
            unsigned u = __builtin_bit_cast(unsigned, hh);
            unsigned r = u + 0x7fffu + ((u >> 16) & 1u);       // RNE
            Bf[T] = (short)(r >> 16);
            float hi = __builtin_bit_cast(float, r & 0xffff0000u);
            rq = __builtin_fmaf(hh, wd7[T], rq);
            rq = __builtin_fmaf(-hi, w7b[T], rq);
        }
        Bf[5] = f2bf(rq);
    }

    // ---- tail: acc_255 exact from fp32 hl ----
    float ap = 0.f;
#pragma unroll
    for (int T = 0; T < 5; ++T) ap = __builtin_fmaf(hl[T], wd7[T], ap);
    ap += __shfl_xor(ap, 16);
    ap += __shfl_xor(ap, 32);
    float accF = ap + biasK;
    if (q == 1) out[(size_t)(NT - 1) * NVEH + veh] = pos + 0.1f * accF;
    if (q == 2) out[(size_t)NT * NVEH + veh]       = spd + 0.1f * accF;

    // ---- final h, c (c unscaled from cst2) ----
    const int oH = NT * NVEH + NVEH;
    const int oC = oH + NVEH * H;
#pragma unroll
    for (int T = 0; T < 5; ++T) {
        int j = 5 * q + T;
        out[oH + veh * H + j] = hl[T];
        out[oC + veh * H + j] = cst2[T] * IN2L;
    }
}

extern "C" void kernel_launch(void* const* d_in, const int* in_sizes, int n_in,
                              void* d_out, int out_size, void* d_ws, size_t ws_size,
                              hipStream_t stream) {
    const float* lead  = (const float*)d_in[0];
    const float* inits = (const float*)d_in[1];
    const float* h0    = (const float*)d_in[2];
    const float* c0    = (const float*)d_in[3];
    const float* W     = (const float*)d_in[4];
    const float* U     = (const float*)d_in[5];
    const float* b     = (const float*)d_in[6];
    const float* Wd    = (const float*)d_in[7];
    const float* bd    = (const float*)d_in[8];
    float* out = (float*)d_out;

    rnncf_kernel<<<NVEH / 64, 256, 0, stream>>>(lead, inits, h0, c0, W, U, b, Wd, bd, out);
}